// Round 1
// baseline (389.333 us; speedup 1.0000x reference)
//
#include <hip/hip_runtime.h>
#include <math.h>

#define NN 512
#define DD 64
#define HH 8
#define DHH 8
#define FF 256
#define BT 96
#define ROWS_TOTAL (BT*NN)   // 49152
constexpr float EPS = 1e-5f;
constexpr float RSQRT_DH = 0.35355339059327373f;  // 1/sqrt(8)

// ---------------- K1: fused QKV projection ----------------
// out layout: [bt][h][n][dh]
__global__ __launch_bounds__(192) void k_qkv(
    const float* __restrict__ x,
    const float* __restrict__ Wq, const float* __restrict__ bq,
    const float* __restrict__ Wk, const float* __restrict__ bk,
    const float* __restrict__ Wv, const float* __restrict__ bv,
    float* __restrict__ qo, float* __restrict__ ko, float* __restrict__ vo)
{
    const int c = threadIdx.x & 63;
    const int seg = threadIdx.x >> 6;          // 0=q 1=k 2=v
    const float* W   = (seg==0) ? Wq : (seg==1 ? Wk : Wv);
    const float* bp  = (seg==0) ? bq : (seg==1 ? bk : bv);
    float* outp      = (seg==0) ? qo : (seg==1 ? ko : vo);
    float wcol[64];
    #pragma unroll
    for (int d=0; d<64; ++d) wcol[d] = W[d*64 + c];
    const float bias = bp[c];
    const int h = c >> 3, dh = c & 7;
    const int r0 = blockIdx.x * 64;
    for (int r=0; r<64; ++r) {
        const int row = r0 + r;
        const float4* xr = (const float4*)(x + (size_t)row*64);
        float acc = 0.f;
        #pragma unroll
        for (int i=0;i<16;++i) {
            float4 xv = xr[i];
            acc += xv.x*wcol[4*i] + xv.y*wcol[4*i+1] + xv.z*wcol[4*i+2] + xv.w*wcol[4*i+3];
        }
        const int bt = row >> 9, n = row & 511;
        outp[(((size_t)bt*HH + h)*NN + n)*DHH + dh] = acc + bias;
    }
}

// ---------------- K2: fused attention (online softmax) ----------------
// block = (bt, 32-row n tile); thread = (h = tid>>5, nn = tid&31)
__global__ __launch_bounds__(256) void k_attn(
    const float* __restrict__ q, const float* __restrict__ k,
    const float* __restrict__ v, const float* __restrict__ pb,
    float* __restrict__ ao)
{
    __shared__ float ks[8][32][8];
    __shared__ float vs[8][32][8];
    __shared__ float pbs[32][33];
    const int bt = blockIdx.y;
    const int n0 = blockIdx.x * 32;
    const int tid = threadIdx.x;
    const int h = tid >> 5;
    const int nn = tid & 31;
    const int n = n0 + nn;

    const float4* q4 = (const float4*)(q + (((size_t)bt*HH + h)*NN + n)*DHH);
    float4 qa = q4[0], qb = q4[1];

    float mrun = -1e30f, lrun = 0.f;
    float acc[8];
    #pragma unroll
    for (int i=0;i<8;++i) acc[i]=0.f;

    for (int mc = 0; mc < 16; ++mc) {
        const int m0 = mc * 32;
        // stage k/v chunk: 512 float4 each
        #pragma unroll
        for (int j=0;j<2;++j) {
            int f = tid + j*256;
            int lh = f >> 6, idx = f & 63;
            const float4* srck = (const float4*)(k + (((size_t)bt*HH + lh)*NN + m0)*DHH);
            const float4* srcv = (const float4*)(v + (((size_t)bt*HH + lh)*NN + m0)*DHH);
            ((float4*)ks)[f] = srck[idx];
            ((float4*)vs)[f] = srcv[idx];
        }
        // stage pos_bias tile [32n][32m]
        {
            int r = tid >> 3, c4 = tid & 7;
            const float4* psrc = (const float4*)(pb + (size_t)(n0 + r)*NN + m0);
            float4 pv = psrc[c4];
            pbs[r][c4*4+0] = pv.x; pbs[r][c4*4+1] = pv.y;
            pbs[r][c4*4+2] = pv.z; pbs[r][c4*4+3] = pv.w;
        }
        __syncthreads();

        for (int ms = 0; ms < 32; ms += 8) {
            float p[8];
            #pragma unroll
            for (int jj=0;jj<8;++jj) {
                int m = ms + jj;
                const float4* kr = (const float4*)&ks[h][m][0];
                float4 ka = kr[0], kb = kr[1];
                float s = qa.x*ka.x + qa.y*ka.y + qa.z*ka.z + qa.w*ka.w
                        + qb.x*kb.x + qb.y*kb.y + qb.z*kb.z + qb.w*kb.w;
                p[jj] = s * RSQRT_DH + pbs[nn][m];
            }
            float cmax = p[0];
            #pragma unroll
            for (int jj=1;jj<8;++jj) cmax = fmaxf(cmax, p[jj]);
            float newm = fmaxf(mrun, cmax);
            float scale = __expf(mrun - newm);
            lrun *= scale;
            #pragma unroll
            for (int i=0;i<8;++i) acc[i] *= scale;
            mrun = newm;
            #pragma unroll
            for (int jj=0;jj<8;++jj) {
                int m = ms + jj;
                float e = __expf(p[jj] - mrun);
                lrun += e;
                const float4* vr = (const float4*)&vs[h][m][0];
                float4 va = vr[0], vb = vr[1];
                acc[0] += e*va.x; acc[1] += e*va.y; acc[2] += e*va.z; acc[3] += e*va.w;
                acc[4] += e*vb.x; acc[5] += e*vb.y; acc[6] += e*vb.z; acc[7] += e*vb.w;
            }
        }
        __syncthreads();
    }
    float inv = 1.f / lrun;
    float4 o0 = make_float4(acc[0]*inv, acc[1]*inv, acc[2]*inv, acc[3]*inv);
    float4 o1 = make_float4(acc[4]*inv, acc[5]*inv, acc[6]*inv, acc[7]*inv);
    float4* dst = (float4*)(ao + ((size_t)bt*NN + n)*DD + h*DHH);
    dst[0] = o0; dst[1] = o1;
}

// ---------------- K3: Wo proj + residual + LN1 ----------------
__global__ __launch_bounds__(256) void k_proj_ln1(
    const float* __restrict__ ao, const float* __restrict__ Wo,
    const float* __restrict__ bo, const float* __restrict__ x,
    const float* __restrict__ g1, const float* __restrict__ be1,
    float* __restrict__ y)
{
    const int c = threadIdx.x & 63;
    const int w = blockIdx.x * 4 + (threadIdx.x >> 6);
    const int nwaves = gridDim.x * 4;
    float wcol[64];
    #pragma unroll
    for (int d=0; d<64; ++d) wcol[d] = Wo[d*64 + c];
    const float bc = bo[c], gc = g1[c], bec = be1[c];
    for (int row = w; row < ROWS_TOTAL; row += nwaves) {
        const float4* ar = (const float4*)(ao + (size_t)row*64);
        float o = 0.f;
        #pragma unroll
        for (int i=0;i<16;++i) {
            float4 a = ar[i];
            o += a.x*wcol[4*i] + a.y*wcol[4*i+1] + a.z*wcol[4*i+2] + a.w*wcol[4*i+3];
        }
        float r = x[(size_t)row*64 + c] + o + bc;
        float s = r;
        #pragma unroll
        for (int off=32; off>=1; off>>=1) s += __shfl_xor(s, off);
        float mu = s * (1.f/64.f);
        float d = r - mu;
        float vv = d*d;
        #pragma unroll
        for (int off=32; off>=1; off>>=1) vv += __shfl_xor(vv, off);
        float rstd = rsqrtf(vv*(1.f/64.f) + EPS);
        y[(size_t)row*64 + c] = d * rstd * gc + bec;
    }
}

// ---------------- K4: FFN + residual + LN2 (in-place on y buffer) ----------------
__global__ __launch_bounds__(256) void k_ffn_ln2(
    const float* __restrict__ yin,
    const float* __restrict__ W1, const float* __restrict__ b1,
    const float* __restrict__ W2, const float* __restrict__ b2,
    const float* __restrict__ g2, const float* __restrict__ be2,
    float* __restrict__ out)
{
    __shared__ float y_s[16][64];
    __shared__ float h_s[16][256];
    __shared__ float p_s[4][16][64];
    const int tid = threadIdx.x;
    const int r0 = blockIdx.x * 16;
    // A: stage 16 rows of y
    {
        int r = tid >> 4, i = tid & 15;
        ((float4*)&y_s[r][0])[i] = ((const float4*)(yin + (size_t)(r0+r)*64))[i];
    }
    __syncthreads();
    // B: h = relu(y @ W1 + b1), one F-column per thread
    {
        float w1c[64];
        #pragma unroll
        for (int d=0; d<64; ++d) w1c[d] = W1[d*256 + tid];
        const float b1c = b1[tid];
        for (int r=0; r<16; ++r) {
            const float4* yr = (const float4*)&y_s[r][0];
            float a = 0.f;
            #pragma unroll
            for (int i=0;i<16;++i) {
                float4 yv = yr[i];
                a += yv.x*w1c[4*i] + yv.y*w1c[4*i+1] + yv.z*w1c[4*i+2] + yv.w*w1c[4*i+3];
            }
            h_s[r][tid] = fmaxf(a + b1c, 0.f);
        }
    }
    __syncthreads();
    // C: partial h @ W2 per quarter of K
    {
        const int c = tid & 63, rg = tid >> 6;
        float w2c[64];
        #pragma unroll
        for (int j=0;j<64;++j) w2c[j] = W2[(size_t)(rg*64 + j)*64 + c];
        for (int r=0;r<16;++r) {
            const float4* hr = (const float4*)&h_s[r][rg*64];
            float a = 0.f;
            #pragma unroll
            for (int i=0;i<16;++i) {
                float4 hv = hr[i];
                a += hv.x*w2c[4*i] + hv.y*w2c[4*i+1] + hv.z*w2c[4*i+2] + hv.w*w2c[4*i+3];
            }
            p_s[rg][r][c] = a;
        }
    }
    __syncthreads();
    // D: sum partials + b2 + residual, LN2, write
    {
        const int c = tid & 63, rw = tid >> 6;
        const float bc = b2[c], gc = g2[c], bec = be2[c];
        for (int rr=0; rr<4; ++rr) {
            int r = rw*4 + rr;
            float o = p_s[0][r][c] + p_s[1][r][c] + p_s[2][r][c] + p_s[3][r][c] + bc;
            float z = y_s[r][c] + o;
            float s = z;
            #pragma unroll
            for (int off=32; off>=1; off>>=1) s += __shfl_xor(s, off);
            float mu = s * (1.f/64.f);
            float d = z - mu;
            float vv = d*d;
            #pragma unroll
            for (int off=32; off>=1; off>>=1) vv += __shfl_xor(vv, off);
            float rstd = rsqrtf(vv*(1.f/64.f) + EPS);
            out[(size_t)(r0+r)*64 + c] = d*rstd*gc + bec;
        }
    }
}

extern "C" void kernel_launch(void* const* d_in, const int* in_sizes, int n_in,
                              void* d_out, int out_size, void* d_ws, size_t ws_size,
                              hipStream_t stream)
{
    const float* x  = (const float*)d_in[0];
    const float* Wq = (const float*)d_in[1];
    const float* bq = (const float*)d_in[2];
    const float* Wk = (const float*)d_in[3];
    const float* bk = (const float*)d_in[4];
    const float* Wv = (const float*)d_in[5];
    const float* bv = (const float*)d_in[6];
    const float* Wo = (const float*)d_in[7];
    const float* bo = (const float*)d_in[8];
    const float* pb = (const float*)d_in[9];
    const float* W1 = (const float*)d_in[10];
    const float* b1 = (const float*)d_in[11];
    const float* W2 = (const float*)d_in[12];
    const float* b2 = (const float*)d_in[13];
    const float* g1 = (const float*)d_in[14];
    const float* be1= (const float*)d_in[15];
    const float* g2 = (const float*)d_in[16];
    const float* be2= (const float*)d_in[17];
    float* out = (float*)d_out;
    float* ws  = (float*)d_ws;

    const size_t SZ = (size_t)ROWS_TOTAL * DD;   // 3,145,728 floats
    float* qb  = ws;
    float* kb  = ws + SZ;
    float* vb  = ws + 2*SZ;
    float* aob = ws + 3*SZ;

    k_qkv<<<768, 192, 0, stream>>>(x, Wq,bq, Wk,bk, Wv,bv, qb, kb, vb);
    k_attn<<<dim3(16,96), 256, 0, stream>>>(qb, kb, vb, pb, aob);
    k_proj_ln1<<<512, 256, 0, stream>>>(aob, Wo, bo, x, g1, be1, out);
    k_ffn_ln2<<<3072, 256, 0, stream>>>(out, W1,b1, W2,b2, g2,be2, out);
}